// Round 15
// baseline (105.216 us; speedup 1.0000x reference)
//
#include <hip/hip_runtime.h>
#include <hip/hip_bf16.h>

#define BB 32
#define CC 128
#define OO 128
#define HH 56
#define WW 56
#define KK 4
#define HW 3136
#define WPLANE 147456
#define EPSV 1e-5f

#define NPOS 348                  // 6 rows x 58 cols staged positions
#define BUFB 22528                // bytes per LDS buffer = 1408 units x 16B (incl pad)

typedef __attribute__((ext_vector_type(8))) short short8v;
typedef __attribute__((ext_vector_type(4))) float f32x4;

static __device__ __forceinline__ void gload16(const void* g, void* l) {
    __builtin_amdgcn_global_load_lds((const __attribute__((address_space(1))) void*)g,
                                     (__attribute__((address_space(3))) void*)l, 16, 0, 0);
}

// ---- convert x -> bf16 channel-last [b][h][w][c], + per-(b,h,c) row sums ----
__global__ void convert_pool_kernel(const float* __restrict__ x,
                                    ushort* __restrict__ xbf,
                                    float* __restrict__ pooledp,
                                    ushort* __restrict__ zpage) {
    const int h = blockIdx.x, b = blockIdx.y;
    if (h == 0 && b == 0 && threadIdx.x < 32) zpage[threadIdx.x] = 0;
    __shared__ float4 xl4[1792];               // [c][w4] swizzled, 28672 B
    const float* xp = x + (size_t)(b * CC) * HW + h * WW;

    #pragma unroll
    for (int k = 0; k < 7; ++k) {
        int u = threadIdx.x + k * 256;
        int c = u / 14, w4 = u - c * 14;
        float4 v = *(const float4*)(xp + (size_t)c * HW + w4 * 4);
        xl4[u ^ ((c >> 3) & 7)] = v;
    }
    __syncthreads();

    const float* xf = (const float*)xl4;
    #pragma unroll
    for (int k = 0; k < 4; ++k) {
        int v = threadIdx.x + k * 256;
        if (v < 896) {
            int w = v >> 4, c8 = v & 15;
            int w4 = w >> 2, wo = w & 3;
            short8v res;
            #pragma unroll
            for (int j = 0; j < 8; ++j) {
                int c = c8 * 8 + j;
                int su = (c * 14 + w4) ^ (c8 & 7);
                __hip_bfloat16 hb = __float2bfloat16(xf[su * 4 + wo]);
                res[j] = *(short*)&hb;
            }
            *(short8v*)(xbf + ((size_t)((b * HH + h) * WW + w)) * CC + c8 * 8) = res;
        }
    }

    if (threadIdx.x < 128) {
        int c = threadIdx.x;
        float s = 0.f;
        #pragma unroll
        for (int w4 = 0; w4 < 14; ++w4) {
            float4 v = xl4[(c * 14 + w4) ^ ((c >> 3) & 7)];
            s += v.x + v.y + v.z + v.w;
        }
        pooledp[((size_t)(b * HH + h)) * CC + c] = s;
    }
}

// ---- fused attention + agg_w: grid (b, j, ci) = 1152 blocks ----
// Each block redundantly computes attn for its sample (deterministic: same
// inputs, same order), then writes its aggw slice [b][j][ci][o][c32] coalesced.
// Blocks with (j,ci)==(0,0) also write agg_b.
__global__ void attn_aggw_kernel(const float* __restrict__ pooledp,
                                 const float* __restrict__ fc1_w, const float* __restrict__ fc1_b,
                                 const float* __restrict__ fc2_w, const float* __restrict__ fc2_b,
                                 const float* __restrict__ weight, const float* __restrict__ bias,
                                 ushort* __restrict__ aggw, float* __restrict__ agg_b) {
    const int b   = blockIdx.x / 36;
    const int rem = blockIdx.x % 36;
    const int j   = rem >> 2;
    const int ci  = rem & 3;

    __shared__ float red[8];
    __shared__ float att[4];
    const int tid = threadIdx.x;
    const int lane = tid & 63, wv = tid >> 6;

    if (tid < 128) {
        const int c = tid;
        float s = 0.f;
        for (int h = 0; h < HH; ++h) s += pooledp[((size_t)(b * HH + h)) * CC + c];
        const float pc = s * (1.0f / HW);
        #pragma unroll
        for (int k = 0; k < KK; ++k) {
            float v = pc * fc1_w[k * CC + c];
            for (int off = 32; off > 0; off >>= 1) v += __shfl_down(v, off, 64);
            if (lane == 0) red[k * 2 + wv] = v;
        }
    }
    __syncthreads();
    if (tid == 0) {
        float hk[KK], z[KK], m = -1e30f, den = 0.f;
        #pragma unroll
        for (int k = 0; k < KK; ++k)
            hk[k] = fmaxf(red[k * 2] + red[k * 2 + 1] + fc1_b[k], 0.f);
        #pragma unroll
        for (int k = 0; k < KK; ++k) {
            float t = fc2_b[k];
            #pragma unroll
            for (int jj = 0; jj < KK; ++jj) t += hk[jj] * fc2_w[k * KK + jj];
            z[k] = t; m = fmaxf(m, t);
        }
        #pragma unroll
        for (int k = 0; k < KK; ++k) { z[k] = expf(z[k] - m); den += z[k]; }
        #pragma unroll
        for (int k = 0; k < KK; ++k) att[k] = z[k] / den;
    }
    __syncthreads();
    const float a0 = att[0], a1 = att[1], a2 = att[2], a3 = att[3];

    if (rem == 0 && tid < 128) {
        const int o = tid;
        float s = 0.f;
        #pragma unroll
        for (int k = 0; k < KK; ++k) s += att[k] * bias[k * OO + o];
        agg_b[b * OO + o] = s;
    }

    // aggw slice: 4096 outputs (o, cc), coalesced writes
    ushort* op = aggw + (((size_t)b * 9 + j) * 4 + ci) * 4096;
    #pragma unroll 4
    for (int it = 0; it < 16; ++it) {
        int idx2 = tid + it * 256;
        int cc = idx2 & 31, o = idx2 >> 5;
        int c = ci * 32 + cc;
        size_t wi = ((size_t)(o * CC + c)) * 9 + j;
        float s = a0 * weight[wi]
                + a1 * weight[wi + (size_t)WPLANE]
                + a2 * weight[wi + (size_t)2*WPLANE]
                + a3 * weight[wi + (size_t)3*WPLANE];
        __hip_bfloat16 hb = __float2bfloat16(s);
        op[idx2] = *(ushort*)&hb;
    }
}

// ================= shared conv body (R9 geometry, dbuf, depth-2 A prefetch) =================
static __device__ __forceinline__ void conv_body(
        const ushort* __restrict__ xbf, const ushort* __restrict__ aggw,
        const ushort* __restrict__ zpage, ushort* xs,
        int b, int h0, int wg, int wy, int cf, int kg, int wid, int lane,
        f32x4 (&acc)[4][7]) {
    const ushort* gp[6]; int gstep[6];
    #pragma unroll
    for (int k = 0; k < 6; ++k) {
        int q = wid + 4 * k;
        int un = q * 64 + lane;
        int u = un ^ ((un >> 3) & 7);
        int pos = u >> 2, quad = u & 3;
        int row = pos / 58, col = pos - row * 58;
        int gh = h0 - 1 + row, gw = col - 1;
        bool valid = (pos < NPOS) && (gh >= 0) && (gh < HH) && (gw >= 0) && (gw < WW);
        gp[k] = valid ? (xbf + ((size_t)((b * HH + gh) * WW + gw)) * CC + quad * 8) : zpage;
        gstep[k] = valid ? 32 : 0;
    }

    int blin[7];
    #pragma unroll
    for (int nf = 0; nf < 7; ++nf) {
        int p = wy * 112 + nf * 16 + cf;
        int r = p / 56, w = p - r * 56;
        blin[nf] = (((r + 1) * 58 + (w + 1)) << 6) + kg * 16;
    }

    const ushort* Ab = aggw + ((size_t)b * 36) * 4096 + (size_t)(wg * 64 + cf) * 32 + kg * 8;
    #define ALOAD(mf_, j_, ci_) (*(const short8v*)(Ab + (size_t)((j_) * 4 + (ci_)) * 4096 + (mf_) * 512))

    // depth-2 rolling A prefetch: paA = tap j, paB = tap j+1
    short8v paA[4], paB[4];
    #pragma unroll
    for (int mf = 0; mf < 4; ++mf) paA[mf] = ALOAD(mf, 0, 0);
    #pragma unroll
    for (int mf = 0; mf < 4; ++mf) paB[mf] = ALOAD(mf, 1, 0);

    #pragma unroll
    for (int k = 0; k < 6; ++k) {
        int q = wid + 4 * k;
        if (q < 22) { gload16(gp[k], (char*)xs + q * 1024); gp[k] += gstep[k]; }
    }
    __syncthreads();

    int cur = 0;
    for (int ci = 0; ci < 4; ++ci) {
        if (ci < 3) {
            char* base = (char*)xs + (cur ^ 1) * BUFB;
            #pragma unroll
            for (int k = 0; k < 6; ++k) {
                int q = wid + 4 * k;
                if (q < 22) { gload16(gp[k], base + q * 1024); gp[k] += gstep[k]; }
            }
        }
        const char* xbuf = (const char*)xs + cur * BUFB;

        short8v bfc[7], bfn[7];
        #pragma unroll
        for (int nf = 0; nf < 7; ++nf) {
            int lin = blin[nf] + (-58 - 1) * 64;
            int swz = lin ^ ((lin >> 3) & 0x70);
            bfc[nf] = *(const short8v*)(xbuf + swz);
        }
        #pragma unroll
        for (int j = 0; j < 9; ++j) {
            if (j < 8) {
                const int toff = (((j+1)/3 - 1) * 58 + ((j+1)%3 - 1)) * 64;
                #pragma unroll
                for (int nf = 0; nf < 7; ++nf) {
                    int lin = blin[nf] + toff;
                    int swz = lin ^ ((lin >> 3) & 0x70);
                    bfn[nf] = *(const short8v*)(xbuf + swz);
                }
            }
            short8v ca[4];
            #pragma unroll
            for (int mf = 0; mf < 4; ++mf) { ca[mf] = paA[mf]; paA[mf] = paB[mf]; }
            const int f = j + 2;
            if (f < 9) {
                #pragma unroll
                for (int mf = 0; mf < 4; ++mf) paB[mf] = ALOAD(mf, f, ci);
            } else if (ci < 3) {
                #pragma unroll
                for (int mf = 0; mf < 4; ++mf) paB[mf] = ALOAD(mf, f - 9, ci + 1);
            }
            #pragma unroll
            for (int nf = 0; nf < 7; ++nf) {
                #pragma unroll
                for (int mf = 0; mf < 4; ++mf)
                    acc[mf][nf] = __builtin_amdgcn_mfma_f32_16x16x32_bf16(ca[mf], bfc[nf], acc[mf][nf], 0, 0, 0);
            }
            if (j < 8) {
                #pragma unroll
                for (int nf = 0; nf < 7; ++nf) bfc[nf] = bfn[nf];
            }
        }
        if (ci < 3) __syncthreads();
        cur ^= 1;
    }
    #undef ALOAD
}

// ---- conv, bf16 output to ws (BF16OUT) or fp32 to d_out; psum layout [o][row] ----
template <bool BF16OUT>
__launch_bounds__(256, 2)
__global__ void conv_kernel(const ushort* __restrict__ xbf, const ushort* __restrict__ aggw,
                            const float* __restrict__ agg_b, const ushort* __restrict__ zpage,
                            void* __restrict__ outv,
                            float* __restrict__ psum, float* __restrict__ psumsq) {
    const int lid  = blockIdx.x;
    const int gwid = (lid & 7) * 56 + (lid >> 3);   // XCD swizzle
    const int b = gwid / 14;
    const int t = gwid - b * 14;
    const int h0 = t * 4;
    __shared__ ushort xs[2 * BUFB / 2];   // 45056 B

    const int tid  = threadIdx.x;
    const int lane = tid & 63;
    const int wid  = tid >> 6;
    const int wg = wid & 1, wy = wid >> 1;
    const int cf = lane & 15, kg = lane >> 4;

    f32x4 acc[4][7];
    #pragma unroll
    for (int mf = 0; mf < 4; ++mf)
        #pragma unroll
        for (int nf = 0; nf < 7; ++nf) acc[mf][nf] = (f32x4){0.f, 0.f, 0.f, 0.f};

    conv_body(xbf, aggw, zpage, xs, b, h0, wg, wy, cf, kg, wid, lane, acc);

    #pragma unroll
    for (int mf = 0; mf < 4; ++mf) {
        #pragma unroll
        for (int i = 0; i < 4; ++i) {
            const int o = wg * 64 + mf * 16 + kg * 4 + i;
            const float ab = agg_b[b * OO + o];
            const size_t obase = ((size_t)(b * OO + o)) * HW;
            float s = 0.f, s2 = 0.f;
            #pragma unroll
            for (int nf = 0; nf < 7; ++nf) {
                int p = wy * 112 + nf * 16 + cf;
                int r = p / 56, w = p - r * 56;
                float v = acc[mf][nf][i] + ab;
                if (BF16OUT) {
                    __hip_bfloat16 hb = __float2bfloat16(v);
                    ((ushort*)outv)[obase + (h0 + r) * WW + w] = *(ushort*)&hb;
                } else {
                    ((float*)outv)[obase + (h0 + r) * WW + w] = v;
                }
                s += v; s2 += v * v;
            }
            s  += __shfl_xor(s, 1, 64);  s  += __shfl_xor(s, 2, 64);
            s  += __shfl_xor(s, 4, 64);  s  += __shfl_xor(s, 8, 64);
            s2 += __shfl_xor(s2, 1, 64); s2 += __shfl_xor(s2, 2, 64);
            s2 += __shfl_xor(s2, 4, 64); s2 += __shfl_xor(s2, 8, 64);
            if (cf == 0) {
                int row = (b * 14 + t) * 2 + wy;
                psum[o * 896 + row]   = s;     // [o][row] for coalesced bn2 reads
                psumsq[o * 896 + row] = s2;
            }
        }
    }
}

// ---- fused finstats + BN + ReLU: block = (o, b-quad), 1024 blocks ----
template <bool BF16IN>
__global__ void bn2_kernel(const void* __restrict__ src, float* __restrict__ out,
                           const float* __restrict__ psum, const float* __restrict__ psumsq,
                           const float* __restrict__ gamma, const float* __restrict__ beta) {
    const int o  = blockIdx.x & 127;
    const int bg = blockIdx.x >> 7;      // 0..7
    const int tid = threadIdx.x;
    const int lane = tid & 63, wv = tid >> 6;
    __shared__ float red[8];
    __shared__ float par[2];

    float s = 0.f, s2 = 0.f;
    for (int r = tid; r < 896; r += 256) {
        s  += psum[o * 896 + r];
        s2 += psumsq[o * 896 + r];
    }
    for (int off = 32; off > 0; off >>= 1) {
        s  += __shfl_down(s, off, 64);
        s2 += __shfl_down(s2, off, 64);
    }
    if (lane == 0) { red[wv] = s; red[4 + wv] = s2; }
    __syncthreads();
    if (tid == 0) {
        const float invN = 1.0f / (float)(BB * HW);
        float S  = red[0] + red[1] + red[2] + red[3];
        float S2 = red[4] + red[5] + red[6] + red[7];
        float mean = S * invN;
        float var  = S2 * invN - mean * mean;
        float inv  = rsqrtf(var + EPSV);
        par[0] = gamma[o] * inv;
        par[1] = beta[o] - mean * par[0];
    }
    __syncthreads();
    const float g = par[0], bt = par[1];

    #pragma unroll
    for (int b2 = 0; b2 < 4; ++b2) {
        const int b = bg * 4 + b2;
        const size_t base = ((size_t)(b * OO + o)) * HW;
        for (int u = tid; u < 392; u += 256) {          // 392 = HW/8
            float4 lo, hi;
            if (BF16IN) {
                short8v v = *(const short8v*)((const ushort*)src + base + u * 8);
                #pragma unroll
                for (int jj = 0; jj < 4; ++jj) {
                    ushort uu = (ushort)v[jj];
                    ((float*)&lo)[jj] = fmaxf(__bfloat162float(*(__hip_bfloat16*)&uu) * g + bt, 0.f);
                }
                #pragma unroll
                for (int jj = 0; jj < 4; ++jj) {
                    ushort uu = (ushort)v[4 + jj];
                    ((float*)&hi)[jj] = fmaxf(__bfloat162float(*(__hip_bfloat16*)&uu) * g + bt, 0.f);
                }
            } else {
                float4 v0 = *(const float4*)((const float*)src + base + u * 8);
                float4 v1 = *(const float4*)((const float*)src + base + u * 8 + 4);
                lo.x = fmaxf(v0.x * g + bt, 0.f); lo.y = fmaxf(v0.y * g + bt, 0.f);
                lo.z = fmaxf(v0.z * g + bt, 0.f); lo.w = fmaxf(v0.w * g + bt, 0.f);
                hi.x = fmaxf(v1.x * g + bt, 0.f); hi.y = fmaxf(v1.y * g + bt, 0.f);
                hi.z = fmaxf(v1.z * g + bt, 0.f); hi.w = fmaxf(v1.w * g + bt, 0.f);
            }
            *(float4*)(out + base + u * 8)     = lo;
            *(float4*)(out + base + u * 8 + 4) = hi;
        }
    }
}

extern "C" void kernel_launch(void* const* d_in, const int* in_sizes, int n_in,
                              void* d_out, int out_size, void* d_ws, size_t ws_size,
                              hipStream_t stream) {
    const float* x      = (const float*)d_in[0];
    const float* fc1_w  = (const float*)d_in[1];
    const float* fc1_b  = (const float*)d_in[2];
    const float* fc2_w  = (const float*)d_in[3];
    const float* fc2_b  = (const float*)d_in[4];
    const float* weight = (const float*)d_in[5];
    const float* bias   = (const float*)d_in[6];
    const float* gamma  = (const float*)d_in[7];
    const float* beta   = (const float*)d_in[8];
    float* out = (float*)d_out;

    const size_t XBF_ELEMS  = (size_t)BB * HW * CC;        // 12,845,056
    const size_t AGGW_ELEMS = (size_t)BB * 9 * OO * CC;    //  4,718,592
    const size_t OUT_ELEMS  = (size_t)BB * OO * HW;        // 12,845,056
    ushort* xbf  = (ushort*)d_ws;
    ushort* aggw = xbf + XBF_ELEMS;
    float*  wsf  = (float*)(aggw + AGGW_ELEMS);
    float* pooledp = wsf;                    // 229376
    float* attn    = pooledp + 229376;       // 128 (unused, kept for layout)
    float* agg_b   = attn + 128;             // 4096
    float* psum    = agg_b + 4096;           // 114688 ([o][row])
    float* psumsq  = psum + 114688;          // 114688
    float* sums    = psumsq + 114688;        // 128 (unused)
    float* sumsq   = sums + 128;             // 128 (unused)
    ushort* zpage  = (ushort*)(sumsq + 128); // 32 shorts
    ushort* convout = (ushort*)(zpage + 32); // bf16 conv output (25.7 MB) if ws allows

    const size_t need = (size_t)((char*)(convout + OUT_ELEMS) - (char*)d_ws);
    const bool bf16path = ws_size >= need;

    convert_pool_kernel<<<dim3(HH, BB), 256, 0, stream>>>(x, xbf, pooledp, zpage);
    attn_aggw_kernel<<<dim3(1152), 256, 0, stream>>>(pooledp, fc1_w, fc1_b, fc2_w, fc2_b,
                                                     weight, bias, aggw, agg_b);
    if (bf16path) {
        conv_kernel<true><<<dim3(448), 256, 0, stream>>>(xbf, aggw, agg_b, zpage,
                                                         (void*)convout, psum, psumsq);
        bn2_kernel<true><<<dim3(1024), 256, 0, stream>>>((const void*)convout, out,
                                                         psum, psumsq, gamma, beta);
    } else {
        conv_kernel<false><<<dim3(448), 256, 0, stream>>>(xbf, aggw, agg_b, zpage,
                                                          (void*)out, psum, psumsq);
        bn2_kernel<false><<<dim3(1024), 256, 0, stream>>>((const void*)out, out,
                                                          psum, psumsq, gamma, beta);
    }
}

// Round 16
// 97.026 us; speedup vs baseline: 1.0844x; 1.0844x over previous
//
#include <hip/hip_runtime.h>
#include <hip/hip_bf16.h>

#define BB 32
#define CC 128
#define OO 128
#define HH 56
#define WW 56
#define KK 4
#define HW 3136
#define WPLANE 147456
#define EPSV 1e-5f

#define NPOS 348                  // 6 rows x 58 cols staged positions
#define BUFB 22528                // bytes per LDS buffer = 1408 units x 16B (incl pad)

typedef __attribute__((ext_vector_type(8))) short short8v;
typedef __attribute__((ext_vector_type(4))) float f32x4;

static __device__ __forceinline__ void gload16(const void* g, void* l) {
    __builtin_amdgcn_global_load_lds((const __attribute__((address_space(1))) void*)g,
                                     (__attribute__((address_space(3))) void*)l, 16, 0, 0);
}

// ---- convert x -> bf16 channel-last [b][h][w][c], + per-(b,hq,c) partial sums ----
// Block = (hq, b): 4 consecutive h-rows => 896B contiguous loads per channel.
// LDS [c][57 ushort4], col index XOR-swizzled by (c>>3)&7 (verified: phase-2
// reads across c8 hit 8 distinct banks, 2-way = free). One barrier.
__global__ void convert_pool_kernel(const float* __restrict__ x,
                                    ushort* __restrict__ xbf,
                                    float* __restrict__ pooledp,
                                    ushort* __restrict__ zpage) {
    const int hq = blockIdx.x;          // 0..13
    const int b  = blockIdx.y;
    const int h0 = hq * 4;
    if (hq == 0 && b == 0 && threadIdx.x < 32) zpage[threadIdx.x] = 0;
    __shared__ ushort xl[128 * 57 * 4];  // [c][i'][4] bf16, 58368 B
    const float* xb = x + (size_t)(b * CC) * HW + h0 * WW;
    const int tid = threadIdx.x;

    // phase 1: 7168 float4 units; u -> (c = u/56, i = u%56); addr = xb + c*HW + i*4
    #pragma unroll
    for (int k = 0; k < 28; ++k) {
        int u = tid + k * 256;
        int c = u / 56, i = u - c * 56;
        float4 v = *(const float4*)(xb + (size_t)c * HW + i * 4);
        ushort4 r;
        __hip_bfloat16 b0 = __float2bfloat16(v.x);
        __hip_bfloat16 b1 = __float2bfloat16(v.y);
        __hip_bfloat16 b2 = __float2bfloat16(v.z);
        __hip_bfloat16 b3 = __float2bfloat16(v.w);
        r.x = *(ushort*)&b0; r.y = *(ushort*)&b1;
        r.z = *(ushort*)&b2; r.w = *(ushort*)&b3;
        *(ushort4*)(&xl[(c * 57 + (i ^ ((c >> 3) & 7))) * 4]) = r;
    }
    __syncthreads();

    // phase 2: 3584 ushort8 units; v -> (row, w, c8), c8 fastest for coalesced stores
    #pragma unroll
    for (int k = 0; k < 14; ++k) {
        int v = tid + k * 256;
        int row = v / 896, rem = v - row * 896;
        int w = rem >> 4, c8 = rem & 15;
        int i = row * 14 + (w >> 2);
        int e = w & 3;
        short8v r;
        #pragma unroll
        for (int j = 0; j < 8; ++j) {
            int c = c8 * 8 + j;                       // c>>3 == c8
            r[j] = (short)xl[(c * 57 + (i ^ (c8 & 7))) * 4 + e];
        }
        *(short8v*)(xbf + ((size_t)((b * HH + h0 + row) * WW + w)) * CC + c8 * 8) = r;
    }

    // pooling partial per (b, hq, c) from bf16 LDS (error negligible vs bf16 conv)
    if (tid < 128) {
        const int c = tid;
        float s = 0.f;
        #pragma unroll
        for (int i = 0; i < 56; ++i) {
            const ushort* q = &xl[(c * 57 + (i ^ ((c >> 3) & 7))) * 4];
            #pragma unroll
            for (int e = 0; e < 4; ++e) {
                ushort u = q[e];
                s += __bfloat162float(*(__hip_bfloat16*)&u);
            }
        }
        pooledp[((size_t)(b * 14 + hq)) * CC + c] = s;
    }
}

// ---- fused attention + agg_w: grid (b, j, ci) = 1152 blocks ----
__global__ void attn_aggw_kernel(const float* __restrict__ pooledp,
                                 const float* __restrict__ fc1_w, const float* __restrict__ fc1_b,
                                 const float* __restrict__ fc2_w, const float* __restrict__ fc2_b,
                                 const float* __restrict__ weight, const float* __restrict__ bias,
                                 ushort* __restrict__ aggw, float* __restrict__ agg_b) {
    const int b   = blockIdx.x / 36;
    const int rem = blockIdx.x % 36;
    const int j   = rem >> 2;
    const int ci  = rem & 3;

    __shared__ float red[8];
    __shared__ float att[4];
    const int tid = threadIdx.x;
    const int lane = tid & 63, wv = tid >> 6;

    if (tid < 128) {
        const int c = tid;
        float s = 0.f;
        #pragma unroll
        for (int h = 0; h < 14; ++h) s += pooledp[((size_t)(b * 14 + h)) * CC + c];
        const float pc = s * (1.0f / HW);
        #pragma unroll
        for (int k = 0; k < KK; ++k) {
            float v = pc * fc1_w[k * CC + c];
            for (int off = 32; off > 0; off >>= 1) v += __shfl_down(v, off, 64);
            if (lane == 0) red[k * 2 + wv] = v;
        }
    }
    __syncthreads();
    if (tid == 0) {
        float hk[KK], z[KK], m = -1e30f, den = 0.f;
        #pragma unroll
        for (int k = 0; k < KK; ++k)
            hk[k] = fmaxf(red[k * 2] + red[k * 2 + 1] + fc1_b[k], 0.f);
        #pragma unroll
        for (int k = 0; k < KK; ++k) {
            float t = fc2_b[k];
            #pragma unroll
            for (int jj = 0; jj < KK; ++jj) t += hk[jj] * fc2_w[k * KK + jj];
            z[k] = t; m = fmaxf(m, t);
        }
        #pragma unroll
        for (int k = 0; k < KK; ++k) { z[k] = expf(z[k] - m); den += z[k]; }
        #pragma unroll
        for (int k = 0; k < KK; ++k) att[k] = z[k] / den;
    }
    __syncthreads();
    const float a0 = att[0], a1 = att[1], a2 = att[2], a3 = att[3];

    if (rem == 0 && tid < 128) {
        const int o = tid;
        float s = 0.f;
        #pragma unroll
        for (int k = 0; k < KK; ++k) s += att[k] * bias[k * OO + o];
        agg_b[b * OO + o] = s;
    }

    ushort* op = aggw + (((size_t)b * 9 + j) * 4 + ci) * 4096;
    #pragma unroll 4
    for (int it = 0; it < 16; ++it) {
        int idx2 = tid + it * 256;
        int cc = idx2 & 31, o = idx2 >> 5;
        int c = ci * 32 + cc;
        size_t wi = ((size_t)(o * CC + c)) * 9 + j;
        float s = a0 * weight[wi]
                + a1 * weight[wi + (size_t)WPLANE]
                + a2 * weight[wi + (size_t)2*WPLANE]
                + a3 * weight[wi + (size_t)3*WPLANE];
        __hip_bfloat16 hb = __float2bfloat16(s);
        op[idx2] = *(ushort*)&hb;
    }
}

// ================= shared conv body (R9/R14 geometry, dbuf, depth-1 A prefetch) =================
static __device__ __forceinline__ void conv_body(
        const ushort* __restrict__ xbf, const ushort* __restrict__ aggw,
        const ushort* __restrict__ zpage, ushort* xs,
        int b, int h0, int wg, int wy, int cf, int kg, int wid, int lane,
        f32x4 (&acc)[4][7]) {
    const ushort* gp[6]; int gstep[6];
    #pragma unroll
    for (int k = 0; k < 6; ++k) {
        int q = wid + 4 * k;
        int un = q * 64 + lane;
        int u = un ^ ((un >> 3) & 7);
        int pos = u >> 2, quad = u & 3;
        int row = pos / 58, col = pos - row * 58;
        int gh = h0 - 1 + row, gw = col - 1;
        bool valid = (pos < NPOS) && (gh >= 0) && (gh < HH) && (gw >= 0) && (gw < WW);
        gp[k] = valid ? (xbf + ((size_t)((b * HH + gh) * WW + gw)) * CC + quad * 8) : zpage;
        gstep[k] = valid ? 32 : 0;
    }

    int blin[7];
    #pragma unroll
    for (int nf = 0; nf < 7; ++nf) {
        int p = wy * 112 + nf * 16 + cf;
        int r = p / 56, w = p - r * 56;
        blin[nf] = (((r + 1) * 58 + (w + 1)) << 6) + kg * 16;
    }

    const ushort* Ab = aggw + ((size_t)b * 36) * 4096 + (size_t)(wg * 64 + cf) * 32 + kg * 8;
    #define ALOAD(mf_, j_, ci_) (*(const short8v*)(Ab + (size_t)((j_) * 4 + (ci_)) * 4096 + (mf_) * 512))

    short8v pa[4];
    #pragma unroll
    for (int mf = 0; mf < 4; ++mf) pa[mf] = ALOAD(mf, 0, 0);

    #pragma unroll
    for (int k = 0; k < 6; ++k) {
        int q = wid + 4 * k;
        if (q < 22) { gload16(gp[k], (char*)xs + q * 1024); gp[k] += gstep[k]; }
    }
    __syncthreads();

    int cur = 0;
    for (int ci = 0; ci < 4; ++ci) {
        if (ci < 3) {
            char* base = (char*)xs + (cur ^ 1) * BUFB;
            #pragma unroll
            for (int k = 0; k < 6; ++k) {
                int q = wid + 4 * k;
                if (q < 22) { gload16(gp[k], base + q * 1024); gp[k] += gstep[k]; }
            }
        }
        const char* xbuf = (const char*)xs + cur * BUFB;

        short8v bfc[7], bfn[7];
        #pragma unroll
        for (int nf = 0; nf < 7; ++nf) {
            int lin = blin[nf] + (-58 - 1) * 64;
            int swz = lin ^ ((lin >> 3) & 0x70);
            bfc[nf] = *(const short8v*)(xbuf + swz);
        }
        #pragma unroll
        for (int j = 0; j < 9; ++j) {
            if (j < 8) {
                const int toff = (((j+1)/3 - 1) * 58 + ((j+1)%3 - 1)) * 64;
                #pragma unroll
                for (int nf = 0; nf < 7; ++nf) {
                    int lin = blin[nf] + toff;
                    int swz = lin ^ ((lin >> 3) & 0x70);
                    bfn[nf] = *(const short8v*)(xbuf + swz);
                }
            }
            short8v ca[4];
            #pragma unroll
            for (int mf = 0; mf < 4; ++mf) ca[mf] = pa[mf];
            if (j < 8) {
                #pragma unroll
                for (int mf = 0; mf < 4; ++mf) pa[mf] = ALOAD(mf, j + 1, ci);
            } else if (ci < 3) {
                #pragma unroll
                for (int mf = 0; mf < 4; ++mf) pa[mf] = ALOAD(mf, 0, ci + 1);
            }
            #pragma unroll
            for (int nf = 0; nf < 7; ++nf) {
                #pragma unroll
                for (int mf = 0; mf < 4; ++mf)
                    acc[mf][nf] = __builtin_amdgcn_mfma_f32_16x16x32_bf16(ca[mf], bfc[nf], acc[mf][nf], 0, 0, 0);
            }
            if (j < 8) {
                #pragma unroll
                for (int nf = 0; nf < 7; ++nf) bfc[nf] = bfn[nf];
            }
        }
        if (ci < 3) __syncthreads();
        cur ^= 1;
    }
    #undef ALOAD
}

// ---- conv, bf16 output to ws (BF16OUT) or fp32 to d_out; psum layout [o][row] ----
template <bool BF16OUT>
__launch_bounds__(256, 2)
__global__ void conv_kernel(const ushort* __restrict__ xbf, const ushort* __restrict__ aggw,
                            const float* __restrict__ agg_b, const ushort* __restrict__ zpage,
                            void* __restrict__ outv,
                            float* __restrict__ psum, float* __restrict__ psumsq) {
    const int lid  = blockIdx.x;
    const int gwid = (lid & 7) * 56 + (lid >> 3);   // XCD swizzle
    const int b = gwid / 14;
    const int t = gwid - b * 14;
    const int h0 = t * 4;
    __shared__ ushort xs[2 * BUFB / 2];   // 45056 B

    const int tid  = threadIdx.x;
    const int lane = tid & 63;
    const int wid  = tid >> 6;
    const int wg = wid & 1, wy = wid >> 1;
    const int cf = lane & 15, kg = lane >> 4;

    f32x4 acc[4][7];
    #pragma unroll
    for (int mf = 0; mf < 4; ++mf)
        #pragma unroll
        for (int nf = 0; nf < 7; ++nf) acc[mf][nf] = (f32x4){0.f, 0.f, 0.f, 0.f};

    conv_body(xbf, aggw, zpage, xs, b, h0, wg, wy, cf, kg, wid, lane, acc);

    #pragma unroll
    for (int mf = 0; mf < 4; ++mf) {
        #pragma unroll
        for (int i = 0; i < 4; ++i) {
            const int o = wg * 64 + mf * 16 + kg * 4 + i;
            const float ab = agg_b[b * OO + o];
            const size_t obase = ((size_t)(b * OO + o)) * HW;
            float s = 0.f, s2 = 0.f;
            #pragma unroll
            for (int nf = 0; nf < 7; ++nf) {
                int p = wy * 112 + nf * 16 + cf;
                int r = p / 56, w = p - r * 56;
                float v = acc[mf][nf][i] + ab;
                if (BF16OUT) {
                    __hip_bfloat16 hb = __float2bfloat16(v);
                    ((ushort*)outv)[obase + (h0 + r) * WW + w] = *(ushort*)&hb;
                } else {
                    ((float*)outv)[obase + (h0 + r) * WW + w] = v;
                }
                s += v; s2 += v * v;
            }
            s  += __shfl_xor(s, 1, 64);  s  += __shfl_xor(s, 2, 64);
            s  += __shfl_xor(s, 4, 64);  s  += __shfl_xor(s, 8, 64);
            s2 += __shfl_xor(s2, 1, 64); s2 += __shfl_xor(s2, 2, 64);
            s2 += __shfl_xor(s2, 4, 64); s2 += __shfl_xor(s2, 8, 64);
            if (cf == 0) {
                int row = (b * 14 + t) * 2 + wy;
                psum[o * 896 + row]   = s;
                psumsq[o * 896 + row] = s2;
            }
        }
    }
}

// ---- fused finstats + BN + ReLU: block = (o, b-quad), 1024 blocks ----
template <bool BF16IN>
__global__ void bn2_kernel(const void* __restrict__ src, float* __restrict__ out,
                           const float* __restrict__ psum, const float* __restrict__ psumsq,
                           const float* __restrict__ gamma, const float* __restrict__ beta) {
    const int o  = blockIdx.x & 127;
    const int bg = blockIdx.x >> 7;      // 0..7
    const int tid = threadIdx.x;
    const int lane = tid & 63, wv = tid >> 6;
    __shared__ float red[8];
    __shared__ float par[2];

    float s = 0.f, s2 = 0.f;
    for (int r = tid; r < 896; r += 256) {
        s  += psum[o * 896 + r];
        s2 += psumsq[o * 896 + r];
    }
    for (int off = 32; off > 0; off >>= 1) {
        s  += __shfl_down(s, off, 64);
        s2 += __shfl_down(s2, off, 64);
    }
    if (lane == 0) { red[wv] = s; red[4 + wv] = s2; }
    __syncthreads();
    if (tid == 0) {
        const float invN = 1.0f / (float)(BB * HW);
        float S  = red[0] + red[1] + red[2] + red[3];
        float S2 = red[4] + red[5] + red[6] + red[7];
        float mean = S * invN;
        float var  = S2 * invN - mean * mean;
        float inv  = rsqrtf(var + EPSV);
        par[0] = gamma[o] * inv;
        par[1] = beta[o] - mean * par[0];
    }
    __syncthreads();
    const float g = par[0], bt = par[1];

    #pragma unroll
    for (int b2 = 0; b2 < 4; ++b2) {
        const int b = bg * 4 + b2;
        const size_t base = ((size_t)(b * OO + o)) * HW;
        for (int u = tid; u < 392; u += 256) {          // 392 = HW/8
            float4 lo, hi;
            if (BF16IN) {
                short8v v = *(const short8v*)((const ushort*)src + base + u * 8);
                #pragma unroll
                for (int jj = 0; jj < 4; ++jj) {
                    ushort uu = (ushort)v[jj];
                    ((float*)&lo)[jj] = fmaxf(__bfloat162float(*(__hip_bfloat16*)&uu) * g + bt, 0.f);
                }
                #pragma unroll
                for (int jj = 0; jj < 4; ++jj) {
                    ushort uu = (ushort)v[4 + jj];
                    ((float*)&hi)[jj] = fmaxf(__bfloat162float(*(__hip_bfloat16*)&uu) * g + bt, 0.f);
                }
            } else {
                float4 v0 = *(const float4*)((const float*)src + base + u * 8);
                float4 v1 = *(const float4*)((const float*)src + base + u * 8 + 4);
                lo.x = fmaxf(v0.x * g + bt, 0.f); lo.y = fmaxf(v0.y * g + bt, 0.f);
                lo.z = fmaxf(v0.z * g + bt, 0.f); lo.w = fmaxf(v0.w * g + bt, 0.f);
                hi.x = fmaxf(v1.x * g + bt, 0.f); hi.y = fmaxf(v1.y * g + bt, 0.f);
                hi.z = fmaxf(v1.z * g + bt, 0.f); hi.w = fmaxf(v1.w * g + bt, 0.f);
            }
            *(float4*)(out + base + u * 8)     = lo;
            *(float4*)(out + base + u * 8 + 4) = hi;
        }
    }
}

extern "C" void kernel_launch(void* const* d_in, const int* in_sizes, int n_in,
                              void* d_out, int out_size, void* d_ws, size_t ws_size,
                              hipStream_t stream) {
    const float* x      = (const float*)d_in[0];
    const float* fc1_w  = (const float*)d_in[1];
    const float* fc1_b  = (const float*)d_in[2];
    const float* fc2_w  = (const float*)d_in[3];
    const float* fc2_b  = (const float*)d_in[4];
    const float* weight = (const float*)d_in[5];
    const float* bias   = (const float*)d_in[6];
    const float* gamma  = (const float*)d_in[7];
    const float* beta   = (const float*)d_in[8];
    float* out = (float*)d_out;

    const size_t XBF_ELEMS  = (size_t)BB * HW * CC;        // 12,845,056
    const size_t AGGW_ELEMS = (size_t)BB * 9 * OO * CC;    //  4,718,592
    const size_t OUT_ELEMS  = (size_t)BB * OO * HW;        // 12,845,056
    ushort* xbf  = (ushort*)d_ws;
    ushort* aggw = xbf + XBF_ELEMS;
    float*  wsf  = (float*)(aggw + AGGW_ELEMS);
    float* pooledp = wsf;                    // 57344 ([b][14][c])
    float* agg_b   = pooledp + 57344;        // 4096
    float* psum    = agg_b + 4096;           // 114688 ([o][row])
    float* psumsq  = psum + 114688;          // 114688
    ushort* zpage  = (ushort*)(psumsq + 114688); // 32 shorts
    ushort* convout = (ushort*)(zpage + 32); // bf16 conv output (25.7 MB) if ws allows

    const size_t need = (size_t)((char*)(convout + OUT_ELEMS) - (char*)d_ws);
    const bool bf16path = ws_size >= need;

    convert_pool_kernel<<<dim3(14, BB), 256, 0, stream>>>(x, xbf, pooledp, zpage);
    attn_aggw_kernel<<<dim3(1152), 256, 0, stream>>>(pooledp, fc1_w, fc1_b, fc2_w, fc2_b,
                                                     weight, bias, aggw, agg_b);
    if (bf16path) {
        conv_kernel<true><<<dim3(448), 256, 0, stream>>>(xbf, aggw, agg_b, zpage,
                                                         (void*)convout, psum, psumsq);
        bn2_kernel<true><<<dim3(1024), 256, 0, stream>>>((const void*)convout, out,
                                                         psum, psumsq, gamma, beta);
    } else {
        conv_kernel<false><<<dim3(448), 256, 0, stream>>>(xbf, aggw, agg_b, zpage,
                                                          (void*)out, psum, psumsq);
        bn2_kernel<false><<<dim3(1024), 256, 0, stream>>>((const void*)out, out,
                                                          psum, psumsq, gamma, beta);
    }
}